// Round 1
// baseline (997.921 us; speedup 1.0000x reference)
//
#include <hip/hip_runtime.h>
#include <hip/hip_bf16.h>
#include <stdint.h>

// GCN: per layer  X_agg = (A_sym + D^-1) X ;  Y = X_agg @ W ; BN(+gamma,beta) ; relu
// bias b cancels through BN (shift-invariant) -> skipped entirely.
// agg-before-GEMM is exact-math equivalent to reference's GEMM-before-agg.

#define NN 100000
#define EE 1600000
#define HH 256
#define BB 64
#define MPAD 100096   // 782*128, zero-padded rows

typedef __attribute__((ext_vector_type(8))) short short8;
typedef __attribute__((ext_vector_type(4))) float f32x4;

__device__ __forceinline__ float bflo(uint32_t v){ return __uint_as_float(v << 16); }
__device__ __forceinline__ float bfhi(uint32_t v){ return __uint_as_float(v & 0xffff0000u); }
__device__ __forceinline__ uint32_t bfrne(float x){
  uint32_t u = __float_as_uint(x);
  return (u + 0x7fffu + ((u >> 16) & 1u)) >> 16;
}
__device__ __forceinline__ uint32_t bfpack(float a, float b){ return bfrne(a) | (bfrne(b) << 16); }

// ---------------- setup: degree, rsqrt, CSR ----------------
__global__ void k_deg(const int* __restrict__ dst, int* __restrict__ degi){
  for (int e = blockIdx.x * blockDim.x + threadIdx.x; e < EE; e += gridDim.x * blockDim.x)
    atomicAdd(&degi[dst[e]], 1);
}

__global__ void k_dis(const int* __restrict__ degi, float* __restrict__ dis){
  int n = blockIdx.x * 256 + threadIdx.x;
  if (n < NN) dis[n] = rsqrtf((float)degi[n] + 1.0f);
}

__global__ void k_scan1(const int* __restrict__ degi, int* __restrict__ rp, int* __restrict__ bsum){
  __shared__ int lds[256];
  int b = blockIdx.x, t = threadIdx.x;
  int base = b * 1024 + t * 4;
  int v0 = (base + 0 < NN) ? degi[base + 0] : 0;
  int v1 = (base + 1 < NN) ? degi[base + 1] : 0;
  int v2 = (base + 2 < NN) ? degi[base + 2] : 0;
  int v3 = (base + 3 < NN) ? degi[base + 3] : 0;
  int s = v0 + v1 + v2 + v3;
  lds[t] = s; __syncthreads();
  for (int off = 1; off < 256; off <<= 1){
    int x = (t >= off) ? lds[t - off] : 0; __syncthreads();
    lds[t] += x; __syncthreads();
  }
  int excl = lds[t] - s;
  if (t == 255) bsum[b] = lds[255];
  if (base + 0 < NN) rp[base + 0] = excl;
  if (base + 1 < NN) rp[base + 1] = excl + v0;
  if (base + 2 < NN) rp[base + 2] = excl + v0 + v1;
  if (base + 3 < NN) rp[base + 3] = excl + v0 + v1 + v2;
}

__global__ void k_scan2(int* __restrict__ bsum, int nb){
  if (blockIdx.x == 0 && threadIdx.x == 0){
    int run = 0;
    for (int i = 0; i < nb; ++i){ int t = bsum[i]; bsum[i] = run; run += t; }
  }
}

__global__ void k_scan3(int* __restrict__ rp, int* __restrict__ cursor, const int* __restrict__ bsum){
  int b = blockIdx.x, t = threadIdx.x;
  int add = bsum[b];
  int base = b * 1024 + t * 4;
  #pragma unroll
  for (int j = 0; j < 4; ++j){
    int i = base + j;
    if (i < NN){ int v = rp[i] + add; rp[i] = v; cursor[i] = v; }
  }
  if (b == 0 && t == 0) rp[NN] = EE;
}

__global__ void k_fill(const int* __restrict__ src, const int* __restrict__ dst,
                       const float* __restrict__ dis, int* __restrict__ cursor,
                       int* __restrict__ csrc, float* __restrict__ cnrm){
  for (int e = blockIdx.x * blockDim.x + threadIdx.x; e < EE; e += gridDim.x * blockDim.x){
    int s = src[e], d = dst[e];
    int pos = atomicAdd(&cursor[d], 1);
    csrc[pos] = s;
    cnrm[pos] = dis[s] * dis[d];
  }
}

// ---------------- weight transpose to bf16:  Wt[c][k] = W[k][c] ----------------
__global__ void k_wt(const float* __restrict__ W, uint16_t* __restrict__ Wt, int K){
  int i = blockIdx.x * 256 + threadIdx.x;   // i = c*K + k
  if (i >= 256 * K) return;
  int c = i / K, k = i - c * K;
  Wt[i] = (uint16_t)bfrne(W[k * 256 + c]);
}

// ---------------- x (f32) -> bf16, zero-pad rows ----------------
__global__ void k_cvtx(const float* __restrict__ x, uint32_t* __restrict__ Xb){
  int i = blockIdx.x * 256 + threadIdx.x;   // over MPAD*64
  if (i >= MPAD * 64) return;
  int row = i >> 6;
  uint32_t r = 0u;
  if (row < NN){
    int col = (i & 63) * 2;
    r = bfpack(x[row * 128 + col], x[row * 128 + col + 1]);
  }
  Xb[i] = r;
}

// ---------------- aggregation: Xout[row] = sum_e nrm*Xin[src] + (1/deg)*Xin[row] ----------------
template<int K>
__global__ void k_agg(const uint32_t* __restrict__ Xin, const int* __restrict__ rp,
                      const int* __restrict__ csrc, const float* __restrict__ cnrm,
                      const float* __restrict__ dis, uint32_t* __restrict__ Xout){
  constexpr int LPR = K / 2;          // uint lanes per row
  constexpr int RPAR = 256 / LPR;     // rows in parallel
  constexpr int SEQ = 4;
  int lane = threadIdx.x & (LPR - 1);
  int slot = threadIdx.x / LPR;
  int row0 = blockIdx.x * (RPAR * SEQ);
  for (int rr = 0; rr < SEQ; ++rr){
    int row = row0 + rr * RPAR + slot;
    if (row >= MPAD) continue;
    if (row >= NN){ Xout[row * LPR + lane] = 0u; continue; }
    int beg = rp[row], end = rp[row + 1];
    float a0 = 0.f, a1 = 0.f;
    int e = beg;
    for (; e + 4 <= end; e += 4){
      int s0 = csrc[e], s1 = csrc[e + 1], s2 = csrc[e + 2], s3 = csrc[e + 3];
      float w0 = cnrm[e], w1 = cnrm[e + 1], w2 = cnrm[e + 2], w3 = cnrm[e + 3];
      uint32_t v0 = Xin[s0 * LPR + lane];
      uint32_t v1 = Xin[s1 * LPR + lane];
      uint32_t v2 = Xin[s2 * LPR + lane];
      uint32_t v3 = Xin[s3 * LPR + lane];
      a0 += w0 * bflo(v0) + w1 * bflo(v1) + w2 * bflo(v2) + w3 * bflo(v3);
      a1 += w0 * bfhi(v0) + w1 * bfhi(v1) + w2 * bfhi(v2) + w3 * bfhi(v3);
    }
    for (; e < end; ++e){
      int s = csrc[e]; float w = cnrm[e];
      uint32_t v = Xin[s * LPR + lane];
      a0 += w * bflo(v); a1 += w * bfhi(v);
    }
    float dv = dis[row]; float sn = dv * dv;
    uint32_t vs = Xin[row * LPR + lane];
    a0 += sn * bflo(vs); a1 += sn * bfhi(vs);
    Xout[row * LPR + lane] = bfpack(a0, a1);
  }
}

// ---------------- GEMM: C[MPAD][256] = A[MPAD][K] * Bt[256][K]^T  (bf16 MFMA) ----------------
template<int K>
__global__ __launch_bounds__(256) void k_gemm(const uint16_t* __restrict__ A,
                                              const uint16_t* __restrict__ Bt,
                                              float* __restrict__ C){
  // LDS chunk layout: chunk c (16B) at lds + c*8 ushorts; c = k8*128 + row  (k8 in [0,4), row in [0,128))
  __shared__ __align__(16) uint16_t lA[4096];
  __shared__ __align__(16) uint16_t lB[4096];
  int tid = threadIdx.x;
  int l = tid & 63;
  int bm = blockIdx.x, bn = blockIdx.y;
  int c1 = tid, c2 = tid + 256;
  const uint16_t* gA1 = A + (size_t)(bm * 128 + (c1 & 127)) * K + (c1 >> 7) * 8;
  const uint16_t* gA2 = A + (size_t)(bm * 128 + (c2 & 127)) * K + (c2 >> 7) * 8;
  const uint16_t* gB1 = Bt + (size_t)(bn * 128 + (c1 & 127)) * K + (c1 >> 7) * 8;
  const uint16_t* gB2 = Bt + (size_t)(bn * 128 + (c2 & 127)) * K + (c2 >> 7) * 8;

  f32x4 acc[4][4];
  #pragma unroll
  for (int m = 0; m < 4; ++m)
    #pragma unroll
    for (int n = 0; n < 4; ++n){ f32x4 z = {0.f, 0.f, 0.f, 0.f}; acc[m][n] = z; }

  int w = tid >> 6;
  int wr = w >> 1, wc = w & 1;
  int rbase = wr * 64, cbase = wc * 64;
  int lrow = l & 15, lk8 = l >> 4;

  for (int kt = 0; kt < K / 32; ++kt){
    short8 ra1 = *(const short8*)(gA1 + kt * 32);
    short8 ra2 = *(const short8*)(gA2 + kt * 32);
    short8 rb1 = *(const short8*)(gB1 + kt * 32);
    short8 rb2 = *(const short8*)(gB2 + kt * 32);
    __syncthreads();
    *(short8*)(lA + c1 * 8) = ra1;
    *(short8*)(lA + c2 * 8) = ra2;
    *(short8*)(lB + c1 * 8) = rb1;
    *(short8*)(lB + c2 * 8) = rb2;
    __syncthreads();
    short8 afr[4], bfr[4];
    #pragma unroll
    for (int m = 0; m < 4; ++m)
      afr[m] = *(const short8*)(lA + (lk8 * 128 + rbase + m * 16 + lrow) * 8);
    #pragma unroll
    for (int n = 0; n < 4; ++n)
      bfr[n] = *(const short8*)(lB + (lk8 * 128 + cbase + n * 16 + lrow) * 8);
    #pragma unroll
    for (int m = 0; m < 4; ++m)
      #pragma unroll
      for (int n = 0; n < 4; ++n)
        acc[m][n] = __builtin_amdgcn_mfma_f32_16x16x32_bf16(afr[m], bfr[n], acc[m][n], 0, 0, 0);
  }

  // C/D layout: col = lane&15, row = (lane>>4)*4 + reg
  int grow0 = bm * 128 + rbase + (l >> 4) * 4;
  int gcol0 = bn * 128 + cbase + (l & 15);
  #pragma unroll
  for (int m = 0; m < 4; ++m){
    #pragma unroll
    for (int n = 0; n < 4; ++n){
      int col = gcol0 + n * 16;
      int r0 = grow0 + m * 16;
      f32x4 v = acc[m][n];
      #pragma unroll
      for (int q = 0; q < 4; ++q)
        C[(size_t)(r0 + q) * 256 + col] = v[q];
    }
  }
}

// ---------------- column stats (sum, sumsq) ----------------
__global__ void k_stats(const float* __restrict__ Y, float* __restrict__ stats){
  int c = threadIdx.x;
  int r0 = blockIdx.x * 256;
  float s = 0.f, s2 = 0.f;
  #pragma unroll 4
  for (int r = r0; r < r0 + 256; ++r){
    float v = Y[(size_t)r * 256 + c];
    s += v; s2 += v * v;
  }
  atomicAdd(&stats[c], s);
  atomicAdd(&stats[256 + c], s2);
}

__global__ void k_finalize(const float* __restrict__ stats, const float* __restrict__ gamma,
                           const float* __restrict__ beta, float* __restrict__ ss){
  int c = threadIdx.x;
  float mean = stats[c] / (float)NN;
  float var  = stats[256 + c] / (float)NN - mean * mean;
  float rstd = rsqrtf(var + 1e-5f);
  float sc = gamma[c] * rstd;
  ss[c] = sc;
  ss[256 + c] = beta[c] - mean * sc;
}

// ---------------- BN + relu + cast to bf16 ----------------
__global__ void k_bnapply(const float* __restrict__ Y, const float* __restrict__ ss,
                          uint32_t* __restrict__ Xout){
  int i = blockIdx.x * 256 + threadIdx.x;    // over MPAD*64, 4 f32 each
  if (i >= MPAD * 64) return;
  f32x4 v = *(const f32x4*)(Y + (size_t)i * 4);
  int c0 = (i & 63) * 4;
  float r0 = fmaxf(v[0] * ss[c0 + 0] + ss[256 + c0 + 0], 0.f);
  float r1 = fmaxf(v[1] * ss[c0 + 1] + ss[256 + c0 + 1], 0.f);
  float r2 = fmaxf(v[2] * ss[c0 + 2] + ss[256 + c0 + 2], 0.f);
  float r3 = fmaxf(v[3] * ss[c0 + 3] + ss[256 + c0 + 3], 0.f);
  uint2 r; r.x = bfpack(r0, r1); r.y = bfpack(r2, r3);
  ((uint2*)Xout)[i] = r;
}

// ---------------- segment starts + pooling ----------------
__global__ void k_segstart(const int* __restrict__ batch, int* __restrict__ seg){
  int g = threadIdx.x;
  if (g > BB) return;
  if (g == BB){ seg[BB] = NN; return; }
  int lo = 0, hi = NN;
  while (lo < hi){ int mid = (lo + hi) >> 1; if (batch[mid] < g) lo = mid + 1; else hi = mid; }
  seg[g] = lo;
}

__global__ void k_pool(const uint32_t* __restrict__ X, const int* __restrict__ seg,
                       float* __restrict__ out){
  int g = blockIdx.x, t = threadIdx.x;    // 128 threads, 2 cols each
  int s = seg[g], e = seg[g + 1];
  float sm0 = 0.f, sm1 = 0.f, mx0 = 0.f, mx1 = 0.f;
  #pragma unroll 4
  for (int r = s; r < e; ++r){
    uint32_t v = X[(size_t)r * 128 + t];
    float a = bflo(v), b2 = bfhi(v);
    sm0 += a; sm1 += b2;
    mx0 = fmaxf(mx0, a); mx1 = fmaxf(mx1, b2);
  }
  float inv = 1.0f / (float)(e - s);
  out[g * 512 + 2 * t] = sm0 * inv;
  out[g * 512 + 2 * t + 1] = sm1 * inv;
  out[g * 512 + 256 + 2 * t] = mx0;
  out[g * 512 + 256 + 2 * t + 1] = mx1;
}

// ---------------- launch ----------------
extern "C" void kernel_launch(void* const* d_in, const int* in_sizes, int n_in,
                              void* d_out, int out_size, void* d_ws, size_t ws_size,
                              hipStream_t stream){
  const float* x     = (const float*)d_in[0];
  const float* W0    = (const float*)d_in[1];
  const float* Wr    = (const float*)d_in[2];
  const float* gamma = (const float*)d_in[4];
  const float* beta  = (const float*)d_in[5];
  const int*   ei    = (const int*)d_in[6];
  const int*   batch = (const int*)d_in[7];
  const int* esrc = ei;
  const int* edst = ei + EE;
  float* out = (float*)d_out;

  char* base = (char*)d_ws;
  size_t off = 0;
  auto alloc = [&](size_t b)->char*{
    char* p = base + off; off = (off + b + 255) & ~(size_t)255; return p;
  };
  uint32_t* Xbuf = (uint32_t*)alloc((size_t)MPAD * 128 * 4);  // bf16 [MPAD][<=256]
  uint32_t* Xagg = (uint32_t*)alloc((size_t)MPAD * 128 * 4);
  float*    Y    = (float*)   alloc((size_t)MPAD * 256 * 4);
  uint16_t* Wt0  = (uint16_t*)alloc(256 * 128 * 2);
  uint16_t* Wt1  = (uint16_t*)alloc(256 * 256 * 2);
  uint16_t* Wt2  = (uint16_t*)alloc(256 * 256 * 2);
  int*   degi   = (int*)  alloc((size_t)NN * 4);
  float* dis    = (float*)alloc((size_t)NN * 4);
  int*   rp     = (int*)  alloc((size_t)(NN + 1) * 4);
  int*   cursor = (int*)  alloc((size_t)NN * 4);
  int*   bsum   = (int*)  alloc(128 * 4);
  int*   csrc   = (int*)  alloc((size_t)EE * 4);
  float* cnrm   = (float*)alloc((size_t)EE * 4);
  float* stats  = (float*)alloc(512 * 4);
  float* ss     = (float*)alloc(512 * 4);
  int*   seg    = (int*)  alloc((BB + 1) * 4);

  hipMemsetAsync(degi, 0, (size_t)NN * 4, stream);
  k_deg<<<2048, 256, 0, stream>>>(edst, degi);
  k_dis<<<391, 256, 0, stream>>>(degi, dis);
  k_scan1<<<98, 256, 0, stream>>>(degi, rp, bsum);
  k_scan2<<<1, 1, 0, stream>>>(bsum, 98);
  k_scan3<<<98, 256, 0, stream>>>(rp, cursor, bsum);
  k_fill<<<2048, 256, 0, stream>>>(esrc, edst, dis, cursor, csrc, cnrm);
  k_wt<<<128, 256, 0, stream>>>(W0, Wt0, 128);
  k_wt<<<256, 256, 0, stream>>>(Wr, Wt1, 256);
  k_wt<<<256, 256, 0, stream>>>(Wr + 256 * 256, Wt2, 256);
  k_cvtx<<<MPAD * 64 / 256, 256, 0, stream>>>(x, Xbuf);

  // layer 1 (K=128)
  k_agg<128><<<MPAD / 16, 256, 0, stream>>>(Xbuf, rp, csrc, cnrm, dis, Xagg);
  k_gemm<128><<<dim3(MPAD / 128, 2), 256, 0, stream>>>((const uint16_t*)Xagg, Wt0, Y);
  hipMemsetAsync(stats, 0, 512 * 4, stream);
  k_stats<<<MPAD / 256, 256, 0, stream>>>(Y, stats);
  k_finalize<<<1, 256, 0, stream>>>(stats, gamma + 0, beta + 0, ss);
  k_bnapply<<<MPAD * 64 / 256, 256, 0, stream>>>(Y, ss, Xbuf);

  // layer 2 (K=256)
  k_agg<256><<<MPAD / 8, 256, 0, stream>>>(Xbuf, rp, csrc, cnrm, dis, Xagg);
  k_gemm<256><<<dim3(MPAD / 128, 2), 256, 0, stream>>>((const uint16_t*)Xagg, Wt1, Y);
  hipMemsetAsync(stats, 0, 512 * 4, stream);
  k_stats<<<MPAD / 256, 256, 0, stream>>>(Y, stats);
  k_finalize<<<1, 256, 0, stream>>>(stats, gamma + 256, beta + 256, ss);
  k_bnapply<<<MPAD * 64 / 256, 256, 0, stream>>>(Y, ss, Xbuf);

  // layer 3 (K=256)
  k_agg<256><<<MPAD / 8, 256, 0, stream>>>(Xbuf, rp, csrc, cnrm, dis, Xagg);
  k_gemm<256><<<dim3(MPAD / 128, 2), 256, 0, stream>>>((const uint16_t*)Xagg, Wt2, Y);
  hipMemsetAsync(stats, 0, 512 * 4, stream);
  k_stats<<<MPAD / 256, 256, 0, stream>>>(Y, stats);
  k_finalize<<<1, 256, 0, stream>>>(stats, gamma + 512, beta + 512, ss);
  k_bnapply<<<MPAD * 64 / 256, 256, 0, stream>>>(Y, ss, Xbuf);

  // pooling
  k_segstart<<<1, 128, 0, stream>>>(batch, seg);
  k_pool<<<BB, 128, 0, stream>>>(Xbuf, seg, out);
}